// Round 1
// baseline (456.109 us; speedup 1.0000x reference)
//
#include <hip/hip_runtime.h>
#include <hip/hip_bf16.h>

typedef __bf16 b16v8 __attribute__((ext_vector_type(8)));
typedef __bf16 b16v4 __attribute__((ext_vector_type(4)));
typedef float  f32x4 __attribute__((ext_vector_type(4)));

#define BB 4
#define SS 2048
#define EE 1024
#define HH 16
#define DD 64

__device__ __forceinline__ void async16(const __bf16* g, __bf16* l) {
  typedef __attribute__((address_space(1))) const unsigned int gu32;
  typedef __attribute__((address_space(3))) unsigned int lu32;
  __builtin_amdgcn_global_load_lds((gu32*)g, (lu32*)l, 16, 0, 0);
}

// ---------------- cast x (fp32 -> bf16), 4 elems/thread ----------------
__global__ __launch_bounds__(256) void cast_x_kernel(const float* __restrict__ in,
                                                     __bf16* __restrict__ out, int n4) {
  int i = blockIdx.x * 256 + threadIdx.x;
  if (i >= n4) return;
  float4 f = ((const float4*)in)[i];
  b16v4 o = {(__bf16)f.x, (__bf16)f.y, (__bf16)f.z, (__bf16)f.w};
  ((b16v4*)out)[i] = o;
}

// -------- cast + transpose weight: w[K][N] fp32 -> wt[N][K] bf16 --------
__global__ __launch_bounds__(256) void cast_transpose(const float* __restrict__ w,
                                                      __bf16* __restrict__ wt, int K, int N) {
  __shared__ float t[32][33];
  int n0 = blockIdx.x * 32, k0 = blockIdx.y * 32;
  int tx = threadIdx.x & 31, ty = threadIdx.x >> 5;  // 32x8
#pragma unroll
  for (int j = 0; j < 32; j += 8)
    t[ty + j][tx] = w[(size_t)(k0 + ty + j) * N + n0 + tx];
  __syncthreads();
#pragma unroll
  for (int j = 0; j < 32; j += 8)
    wt[(size_t)(n0 + ty + j) * K + k0 + tx] = (__bf16)t[tx][ty + j];
}

// ------------- transpose v [BH][S][D] -> vt [BH][D][S] (bf16) -------------
__global__ __launch_bounds__(256) void transpose_v(const __bf16* __restrict__ vb,
                                                   __bf16* __restrict__ vtb) {
  __shared__ __bf16 t[64 * 72];
  const int s0 = blockIdx.x * 64;
  const int bh = blockIdx.y;
  const int tid = threadIdx.x;
  const __bf16* src = vb + ((size_t)bh * SS + s0) * DD;
#pragma unroll
  for (int i = 0; i < 2; ++i) {
    int c = tid + i * 256;
    *(uint4*)(t + (c >> 3) * 72 + (c & 7) * 8) =
        *(const uint4*)(src + (size_t)(c >> 3) * DD + (c & 7) * 8);
  }
  __syncthreads();
  __bf16* dst = vtb + (size_t)bh * DD * SS + s0;
#pragma unroll
  for (int i = 0; i < 2; ++i) {
    int c = tid + i * 256;
    int d = c >> 3, s8 = c & 7;
    union { __bf16 e[8]; uint4 v; } u;
#pragma unroll
    for (int k = 0; k < 8; ++k) u.e[k] = t[(s8 * 8 + k) * 72 + d];
    *(uint4*)(dst + (size_t)d * SS + s8 * 8) = u.v;
  }
}

// ---------------- GEMM C[M][N] = A[M][K] * Bt[N][K]^T (bf16 in) ----------------
// EPI 0: scatter qkv (N=3072) into q/k/v [BH][S][D] bf16. EPI 1: fp32 C0[M][N].
template <int EPI>
__global__ __launch_bounds__(256) void gemm_bt(const __bf16* __restrict__ A,
                                               const __bf16* __restrict__ Bt,
                                               void* C0, void* C1, void* C2,
                                               int M, int N, int K) {
  __shared__ __bf16 a_lds[128 * 32];
  __shared__ __bf16 b_lds[128 * 32];
  const int tid = threadIdx.x;
  const int lane = tid & 63;
  const int w = tid >> 6;
  const int wm = (w >> 1) * 64, wn = (w & 1) * 64;
  const int l16 = lane & 15, quad = lane >> 4;
  const __bf16* Ab = A + (size_t)blockIdx.y * 128 * K;
  const __bf16* Bb = Bt + (size_t)blockIdx.x * 128 * K;
  f32x4 acc[4][4];
#pragma unroll
  for (int i = 0; i < 4; ++i)
#pragma unroll
    for (int j = 0; j < 4; ++j) acc[i][j] = f32x4{0.f, 0.f, 0.f, 0.f};

  for (int k0 = 0; k0 < K; k0 += 32) {
    __syncthreads();
#pragma unroll
    for (int i = 0; i < 2; ++i) {
      int c = tid + i * 256;
      async16(Ab + (size_t)(c >> 2) * K + k0 + (c & 3) * 8, a_lds + c * 8);
    }
#pragma unroll
    for (int i = 0; i < 2; ++i) {
      int c = tid + i * 256;
      async16(Bb + (size_t)(c >> 2) * K + k0 + (c & 3) * 8, b_lds + c * 8);
    }
    __syncthreads();
    b16v8 af[4], bf[4];
#pragma unroll
    for (int t = 0; t < 4; ++t) {
      af[t] = *(const b16v8*)(a_lds + (wm + t * 16 + l16) * 32 + quad * 8);
      bf[t] = *(const b16v8*)(b_lds + (wn + t * 16 + l16) * 32 + quad * 8);
    }
#pragma unroll
    for (int mt = 0; mt < 4; ++mt)
#pragma unroll
      for (int nt = 0; nt < 4; ++nt)
        acc[mt][nt] = __builtin_amdgcn_mfma_f32_16x16x32_bf16(af[mt], bf[nt], acc[mt][nt], 0, 0, 0);
  }

  if (EPI == 0) {
    __bf16* qb = (__bf16*)C0;
    __bf16* kb = (__bf16*)C1;
    __bf16* vb = (__bf16*)C2;
#pragma unroll
    for (int mt = 0; mt < 4; ++mt)
#pragma unroll
      for (int nt = 0; nt < 4; ++nt)
#pragma unroll
        for (int r = 0; r < 4; ++r) {
          int row = blockIdx.y * 128 + wm + mt * 16 + quad * 4 + r;
          int col = blockIdx.x * 128 + wn + nt * 16 + l16;
          float v = acc[mt][nt][r];
          int b = row >> 11, s = row & 2047;
          int sec = col >> 10, cc = col & 1023;
          int h = cc >> 6, d = cc & 63;
          size_t idx = (((size_t)(b * HH + h) * SS + s) << 6) + d;
          __bf16 bv = (__bf16)v;
          if (sec == 0) qb[idx] = bv;
          else if (sec == 1) kb[idx] = bv;
          else vb[idx] = bv;
        }
  } else {
    float* out = (float*)C0;
#pragma unroll
    for (int mt = 0; mt < 4; ++mt)
#pragma unroll
      for (int nt = 0; nt < 4; ++nt)
#pragma unroll
        for (int r = 0; r < 4; ++r) {
          int row = blockIdx.y * 128 + wm + mt * 16 + quad * 4 + r;
          int col = blockIdx.x * 128 + wn + nt * 16 + l16;
          out[(size_t)row * N + col] = acc[mt][nt][r];
        }
  }
}

// ---------------- flash attention (causal), 128 q-rows per block ----------------
__global__ __launch_bounds__(256) void attn_kernel(const __bf16* __restrict__ qb,
                                                   const __bf16* __restrict__ kb,
                                                   const __bf16* __restrict__ vtb,
                                                   __bf16* __restrict__ y) {
  __shared__ __bf16 k_lds[128 * 72];    // K tile [key][d], pad 72
  __shared__ __bf16 vt_lds[64 * 136];   // V^T tile [d][key], pad 136
  __shared__ __bf16 p_lds[4][32 * 72];  // per-wave P chunk [32 q][64 key pad 72]
  const int tid = threadIdx.x;
  const int lane = tid & 63;
  const int w = tid >> 6;
  const int l16 = lane & 15, quad = lane >> 4;
  const int qt = blockIdx.x, bh = blockIdx.y;
  const int b = bh >> 4, h = bh & 15;
  const __bf16* kbase = kb + (size_t)bh * SS * DD;
  const __bf16* vtbase = vtb + (size_t)bh * DD * SS;

  // Q fragments held in registers (rows w*32 .. w*32+31 of this q-tile)
  b16v8 qf[2][2];
#pragma unroll
  for (int mt = 0; mt < 2; ++mt)
#pragma unroll
    for (int ks = 0; ks < 2; ++ks) {
      int qrow = qt * 128 + w * 32 + mt * 16 + l16;
      qf[mt][ks] = *(const b16v8*)(qb + ((size_t)bh * SS + qrow) * DD + ks * 32 + quad * 8);
    }

  f32x4 o[2][4];
#pragma unroll
  for (int mt = 0; mt < 2; ++mt)
#pragma unroll
    for (int nt = 0; nt < 4; ++nt) o[mt][nt] = f32x4{0.f, 0.f, 0.f, 0.f};
  float mrow[2][4], lrow[2][4];
#pragma unroll
  for (int mt = 0; mt < 2; ++mt)
#pragma unroll
    for (int r = 0; r < 4; ++r) { mrow[mt][r] = -1e30f; lrow[mt][r] = 0.f; }

  for (int j = 0; j <= qt; ++j) {
    // stage K and V^T tiles
#pragma unroll
    for (int i = 0; i < 4; ++i) {
      int c = tid + i * 256;
      *(uint4*)(k_lds + (c >> 3) * 72 + (c & 7) * 8) =
          *(const uint4*)(kbase + (size_t)(j * 128 + (c >> 3)) * DD + (c & 7) * 8);
    }
#pragma unroll
    for (int i = 0; i < 4; ++i) {
      int c = tid + i * 256;
      *(uint4*)(vt_lds + (c >> 4) * 136 + (c & 15) * 8) =
          *(const uint4*)(vtbase + (size_t)(c >> 4) * SS + j * 128 + (c & 15) * 8);
    }
    __syncthreads();

    // S = Q K^T  (wave w owns q-rows w*32..+32, all 128 keys)
    f32x4 s[2][8];
#pragma unroll
    for (int mt = 0; mt < 2; ++mt)
#pragma unroll
      for (int nt = 0; nt < 8; ++nt) s[mt][nt] = f32x4{0.f, 0.f, 0.f, 0.f};
#pragma unroll
    for (int nt = 0; nt < 8; ++nt) {
      b16v8 kf0 = *(const b16v8*)(k_lds + (nt * 16 + l16) * 72 + quad * 8);
      b16v8 kf1 = *(const b16v8*)(k_lds + (nt * 16 + l16) * 72 + 32 + quad * 8);
#pragma unroll
      for (int mt = 0; mt < 2; ++mt) {
        s[mt][nt] = __builtin_amdgcn_mfma_f32_16x16x32_bf16(qf[mt][0], kf0, s[mt][nt], 0, 0, 0);
        s[mt][nt] = __builtin_amdgcn_mfma_f32_16x16x32_bf16(qf[mt][1], kf1, s[mt][nt], 0, 0, 0);
      }
    }
    // scale + causal mask (only the diagonal tile needs masking)
#pragma unroll
    for (int mt = 0; mt < 2; ++mt)
#pragma unroll
      for (int nt = 0; nt < 8; ++nt)
#pragma unroll
        for (int r = 0; r < 4; ++r) {
          float sv = s[mt][nt][r] * 0.125f;
          if (j == qt) {
            int qg = w * 32 + mt * 16 + quad * 4 + r;
            int kg = nt * 16 + l16;
            if (kg > qg) sv = -1e30f;
          }
          s[mt][nt][r] = sv;
        }
    // row max (in-thread over nt, then 16-lane butterfly)
    float mx[2][4];
#pragma unroll
    for (int mt = 0; mt < 2; ++mt)
#pragma unroll
      for (int r = 0; r < 4; ++r) {
        float m = s[mt][0][r];
#pragma unroll
        for (int nt = 1; nt < 8; ++nt) m = fmaxf(m, s[mt][nt][r]);
        mx[mt][r] = m;
      }
#pragma unroll
    for (int off = 1; off < 16; off <<= 1)
#pragma unroll
      for (int mt = 0; mt < 2; ++mt)
#pragma unroll
        for (int r = 0; r < 4; ++r) mx[mt][r] = fmaxf(mx[mt][r], __shfl_xor(mx[mt][r], off));
    float al[2][4];
#pragma unroll
    for (int mt = 0; mt < 2; ++mt)
#pragma unroll
      for (int r = 0; r < 4; ++r) {
        float mn = fmaxf(mrow[mt][r], mx[mt][r]);
        al[mt][r] = __expf(mrow[mt][r] - mn);
        mrow[mt][r] = mn;
      }
    // rescale O
#pragma unroll
    for (int mt = 0; mt < 2; ++mt)
#pragma unroll
      for (int nt = 0; nt < 4; ++nt)
#pragma unroll
        for (int r = 0; r < 4; ++r) o[mt][nt][r] *= al[mt][r];
    // P = exp(S - m), row sums
    float rs[2][4];
#pragma unroll
    for (int mt = 0; mt < 2; ++mt)
#pragma unroll
      for (int r = 0; r < 4; ++r) rs[mt][r] = 0.f;
#pragma unroll
    for (int mt = 0; mt < 2; ++mt)
#pragma unroll
      for (int nt = 0; nt < 8; ++nt)
#pragma unroll
        for (int r = 0; r < 4; ++r) {
          float pv = __expf(s[mt][nt][r] - mrow[mt][r]);
          s[mt][nt][r] = pv;
          rs[mt][r] += pv;
        }
#pragma unroll
    for (int off = 1; off < 16; off <<= 1)
#pragma unroll
      for (int mt = 0; mt < 2; ++mt)
#pragma unroll
        for (int r = 0; r < 4; ++r) rs[mt][r] += __shfl_xor(rs[mt][r], off);
#pragma unroll
    for (int mt = 0; mt < 2; ++mt)
#pragma unroll
      for (int r = 0; r < 4; ++r) lrow[mt][r] = lrow[mt][r] * al[mt][r] + rs[mt][r];

    // O += P V  via per-wave LDS round-trip, two 64-key chunks
    __bf16* pw = p_lds[w];
#pragma unroll
    for (int cch = 0; cch < 2; ++cch) {
#pragma unroll
      for (int mt = 0; mt < 2; ++mt)
#pragma unroll
        for (int nt2 = 0; nt2 < 4; ++nt2)
#pragma unroll
          for (int r = 0; r < 4; ++r)
            pw[(mt * 16 + quad * 4 + r) * 72 + nt2 * 16 + l16] = (__bf16)s[mt][cch * 4 + nt2][r];
      __syncthreads();
#pragma unroll
      for (int ks = 0; ks < 2; ++ks) {
        b16v8 vf[4];
#pragma unroll
        for (int ntO = 0; ntO < 4; ++ntO)
          vf[ntO] = *(const b16v8*)(vt_lds + (ntO * 16 + l16) * 136 + (cch * 2 + ks) * 32 + quad * 8);
#pragma unroll
        for (int mt = 0; mt < 2; ++mt) {
          b16v8 af = *(const b16v8*)(pw + (mt * 16 + l16) * 72 + ks * 32 + quad * 8);
#pragma unroll
          for (int ntO = 0; ntO < 4; ++ntO)
            o[mt][ntO] = __builtin_amdgcn_mfma_f32_16x16x32_bf16(af, vf[ntO], o[mt][ntO], 0, 0, 0);
        }
      }
      __syncthreads();
    }
  }

  // finalize: O / l, write y[b][s][h*64+d] bf16
#pragma unroll
  for (int mt = 0; mt < 2; ++mt)
#pragma unroll
    for (int r = 0; r < 4; ++r) {
      float inv = 1.0f / lrow[mt][r];
      int srow = qt * 128 + w * 32 + mt * 16 + quad * 4 + r;
#pragma unroll
      for (int ntO = 0; ntO < 4; ++ntO)
        y[((size_t)b * SS + srow) * EE + h * 64 + ntO * 16 + l16] =
            (__bf16)(o[mt][ntO][r] * inv);
    }
}

extern "C" void kernel_launch(void* const* d_in, const int* in_sizes, int n_in,
                              void* d_out, int out_size, void* d_ws, size_t ws_size,
                              hipStream_t stream) {
  (void)in_sizes; (void)n_in; (void)out_size; (void)ws_size;
  const float* x = (const float*)d_in[0];
  const float* w_att = (const float*)d_in[1];
  const float* w_proj = (const float*)d_in[2];
  float* out = (float*)d_out;

  char* ws = (char*)d_ws;
  size_t off = 0;
  auto alloc = [&](size_t elems) { __bf16* p = (__bf16*)(ws + off); off += elems * 2; return p; };
  __bf16* xb = alloc(8388608);     // x bf16; reused as y after attention
  __bf16* qb = alloc(8388608);     // [BH][S][D]
  __bf16* kb = alloc(8388608);     // [BH][S][D]
  __bf16* vb = alloc(8388608);     // [BH][S][D]
  __bf16* vtb = alloc(8388608);    // [BH][D][S]
  __bf16* watt = alloc(3145728);   // w_att^T  [3072][1024]
  __bf16* wproj = alloc(1048576);  // w_proj^T [1024][1024]

  cast_x_kernel<<<8192, 256, 0, stream>>>(x, xb, 2097152);
  cast_transpose<<<dim3(96, 32), 256, 0, stream>>>(w_att, watt, 1024, 3072);
  cast_transpose<<<dim3(32, 32), 256, 0, stream>>>(w_proj, wproj, 1024, 1024);
  gemm_bt<0><<<dim3(24, 64), 256, 0, stream>>>(xb, watt, qb, kb, vb, 8192, 3072, 1024);
  transpose_v<<<dim3(32, 64), 256, 0, stream>>>(vb, vtb);
  attn_kernel<<<dim3(16, 64), 256, 0, stream>>>(qb, kb, vtb, xb);
  gemm_bt<1><<<dim3(8, 64), 256, 0, stream>>>(xb, wproj, out, nullptr, nullptr, 8192, 1024, 1024);
}

// Round 2
// 366.914 us; speedup vs baseline: 1.2431x; 1.2431x over previous
//
#include <hip/hip_runtime.h>
#include <hip/hip_bf16.h>

typedef __bf16 b16v8 __attribute__((ext_vector_type(8)));
typedef __bf16 b16v4 __attribute__((ext_vector_type(4)));
typedef float  f32x4 __attribute__((ext_vector_type(4)));

#define BB 4
#define SS 2048
#define EE 1024
#define HH 16
#define DD 64

// 0.125 * log2(e): folds softmax scale + exp->exp2 conversion into q.
#define QSCALE 0.18033688011112042f

__device__ __forceinline__ void async16(const __bf16* g, __bf16* l) {
  typedef __attribute__((address_space(1))) const unsigned int gu32;
  typedef __attribute__((address_space(3))) unsigned int lu32;
  __builtin_amdgcn_global_load_lds((gu32*)g, (lu32*)l, 16, 0, 0);
}

__device__ __forceinline__ f32x4 mfma16x16x16_bf16(b16v4 a, b16v4 b, f32x4 c) {
#if __has_builtin(__builtin_amdgcn_mfma_f32_16x16x16_bf16)
  return __builtin_amdgcn_mfma_f32_16x16x16_bf16(a, b, c, 0, 0, 0);
#else
  typedef short s16v4 __attribute__((ext_vector_type(4)));
  union U { b16v4 h; s16v4 s; };
  U ua, ub; ua.h = a; ub.h = b;
  return __builtin_amdgcn_mfma_f32_16x16x16bf16_1k(ua.s, ub.s, c, 0, 0, 0);
#endif
}

// ---------------- cast x (fp32 -> bf16), 4 elems/thread ----------------
__global__ __launch_bounds__(256) void cast_x_kernel(const float* __restrict__ in,
                                                     __bf16* __restrict__ out, int n4) {
  int i = blockIdx.x * 256 + threadIdx.x;
  if (i >= n4) return;
  float4 f = ((const float4*)in)[i];
  b16v4 o = {(__bf16)f.x, (__bf16)f.y, (__bf16)f.z, (__bf16)f.w};
  ((b16v4*)out)[i] = o;
}

// -------- cast + transpose weight: w[K][N] fp32 -> wt[N][K] bf16 --------
__global__ __launch_bounds__(256) void cast_transpose(const float* __restrict__ w,
                                                      __bf16* __restrict__ wt, int K, int N) {
  __shared__ float t[32][33];
  int n0 = blockIdx.x * 32, k0 = blockIdx.y * 32;
  int tx = threadIdx.x & 31, ty = threadIdx.x >> 5;  // 32x8
#pragma unroll
  for (int j = 0; j < 32; j += 8)
    t[ty + j][tx] = w[(size_t)(k0 + ty + j) * N + n0 + tx];
  __syncthreads();
#pragma unroll
  for (int j = 0; j < 32; j += 8)
    wt[(size_t)(n0 + ty + j) * K + k0 + tx] = (__bf16)t[tx][ty + j];
}

// ------------- transpose v [BH][S][D] -> vt [BH][D][S] (bf16) -------------
__global__ __launch_bounds__(256) void transpose_v(const __bf16* __restrict__ vb,
                                                   __bf16* __restrict__ vtb) {
  __shared__ __bf16 t[64 * 72];
  const int s0 = blockIdx.x * 64;
  const int bh = blockIdx.y;
  const int tid = threadIdx.x;
  const __bf16* src = vb + ((size_t)bh * SS + s0) * DD;
#pragma unroll
  for (int i = 0; i < 2; ++i) {
    int c = tid + i * 256;
    *(uint4*)(t + (c >> 3) * 72 + (c & 7) * 8) =
        *(const uint4*)(src + (size_t)(c >> 3) * DD + (c & 7) * 8);
  }
  __syncthreads();
  __bf16* dst = vtb + (size_t)bh * DD * SS + s0;
#pragma unroll
  for (int i = 0; i < 2; ++i) {
    int c = tid + i * 256;
    int d = c >> 3, s8 = c & 7;
    union { __bf16 e[8]; uint4 v; } u;
#pragma unroll
    for (int k = 0; k < 8; ++k) u.e[k] = t[(s8 * 8 + k) * 72 + d];
    *(uint4*)(dst + (size_t)d * SS + s8 * 8) = u.v;
  }
}

// ---------------- GEMM C[M][N] = A[M][K] * Bt[N][K]^T (bf16 in) ----------------
// EPI 0: scatter qkv (N=3072) into q/k/v [BH][S][D] bf16 (q pre-scaled). EPI 1: fp32 C0.
template <int EPI>
__global__ __launch_bounds__(256) void gemm_bt(const __bf16* __restrict__ A,
                                               const __bf16* __restrict__ Bt,
                                               void* C0, void* C1, void* C2,
                                               int M, int N, int K) {
  __shared__ __bf16 a_lds[128 * 32];
  __shared__ __bf16 b_lds[128 * 32];
  const int tid = threadIdx.x;
  const int lane = tid & 63;
  const int w = tid >> 6;
  const int wm = (w >> 1) * 64, wn = (w & 1) * 64;
  const int l16 = lane & 15, quad = lane >> 4;
  const __bf16* Ab = A + (size_t)blockIdx.y * 128 * K;
  const __bf16* Bb = Bt + (size_t)blockIdx.x * 128 * K;
  f32x4 acc[4][4];
#pragma unroll
  for (int i = 0; i < 4; ++i)
#pragma unroll
    for (int j = 0; j < 4; ++j) acc[i][j] = f32x4{0.f, 0.f, 0.f, 0.f};

  for (int k0 = 0; k0 < K; k0 += 32) {
    __syncthreads();
#pragma unroll
    for (int i = 0; i < 2; ++i) {
      int c = tid + i * 256;
      async16(Ab + (size_t)(c >> 2) * K + k0 + (c & 3) * 8, a_lds + c * 8);
    }
#pragma unroll
    for (int i = 0; i < 2; ++i) {
      int c = tid + i * 256;
      async16(Bb + (size_t)(c >> 2) * K + k0 + (c & 3) * 8, b_lds + c * 8);
    }
    __syncthreads();
    b16v8 af[4], bf[4];
#pragma unroll
    for (int t = 0; t < 4; ++t) {
      af[t] = *(const b16v8*)(a_lds + (wm + t * 16 + l16) * 32 + quad * 8);
      bf[t] = *(const b16v8*)(b_lds + (wn + t * 16 + l16) * 32 + quad * 8);
    }
#pragma unroll
    for (int mt = 0; mt < 4; ++mt)
#pragma unroll
      for (int nt = 0; nt < 4; ++nt)
        acc[mt][nt] = __builtin_amdgcn_mfma_f32_16x16x32_bf16(af[mt], bf[nt], acc[mt][nt], 0, 0, 0);
  }

  if (EPI == 0) {
    __bf16* qb = (__bf16*)C0;
    __bf16* kb = (__bf16*)C1;
    __bf16* vb = (__bf16*)C2;
#pragma unroll
    for (int mt = 0; mt < 4; ++mt)
#pragma unroll
      for (int nt = 0; nt < 4; ++nt)
#pragma unroll
        for (int r = 0; r < 4; ++r) {
          int row = blockIdx.y * 128 + wm + mt * 16 + quad * 4 + r;
          int col = blockIdx.x * 128 + wn + nt * 16 + l16;
          float v = acc[mt][nt][r];
          int b = row >> 11, s = row & 2047;
          int sec = col >> 10, cc = col & 1023;
          int h = cc >> 6, d = cc & 63;
          size_t idx = (((size_t)(b * HH + h) * SS + s) << 6) + d;
          if (sec == 0) qb[idx] = (__bf16)(v * QSCALE);
          else if (sec == 1) kb[idx] = (__bf16)v;
          else vb[idx] = (__bf16)v;
        }
  } else {
    float* out = (float*)C0;
#pragma unroll
    for (int mt = 0; mt < 4; ++mt)
#pragma unroll
      for (int nt = 0; nt < 4; ++nt)
#pragma unroll
        for (int r = 0; r < 4; ++r) {
          int row = blockIdx.y * 128 + wm + mt * 16 + quad * 4 + r;
          int col = blockIdx.x * 128 + wn + nt * 16 + l16;
          out[(size_t)row * N + col] = acc[mt][nt][r];
        }
  }
}

// ---------------- flash attention (causal), S^T/O^T formulation ----------------
// Block p handles q-tiles {15-p, p} (constant 17 j-iters). Wave w owns 32 q-rows.
// S^T = K·Q^T via 16x16x32 (operand swap): C-layout key=quad*4+r, q=l16.
// P^T register layout == B-operand of 16x16x16 => PV with zero data movement.
__global__ __launch_bounds__(256, 3) void attn_kernel(const __bf16* __restrict__ qb,
                                                      const __bf16* __restrict__ kb,
                                                      const __bf16* __restrict__ vtb,
                                                      __bf16* __restrict__ y) {
  __shared__ __bf16 k_lds[128 * 72];    // K tile [key][d], pad 72
  __shared__ __bf16 vt_lds[64 * 130];   // V^T tile [d][key], pad 130 (odd word stride)
  const int tid = threadIdx.x;
  const int lane = tid & 63;
  const int w = tid >> 6;
  const int l16 = lane & 15, quad = lane >> 4;
  const int p = blockIdx.x, bh = blockIdx.y;
  const int b = bh >> 4, h = bh & 15;
  const __bf16* kbase = kb + (size_t)bh * SS * DD;
  const __bf16* vtbase = vtb + (size_t)bh * DD * SS;

#pragma unroll
  for (int t = 0; t < 2; ++t) {
    const int qt = (t == 0) ? (15 - p) : p;

    // Q frags: lane holds Q[q = qt*128 + w*32 + qtile*16 + l16][d = ks*32 + quad*8 + j]
    b16v8 qf[2][2];
#pragma unroll
    for (int qtile = 0; qtile < 2; ++qtile)
#pragma unroll
      for (int ks = 0; ks < 2; ++ks)
        qf[qtile][ks] = *(const b16v8*)(qb + ((size_t)bh * SS + qt * 128 + w * 32 + qtile * 16 + l16) * DD + ks * 32 + quad * 8);

    f32x4 o[4][2];  // O^T[d = dt*16+quad*4+r][q = qtile*16+l16]
#pragma unroll
    for (int dt = 0; dt < 4; ++dt)
#pragma unroll
      for (int qtile = 0; qtile < 2; ++qtile) o[dt][qtile] = f32x4{0.f, 0.f, 0.f, 0.f};
    float mrow[2] = {-1e30f, -1e30f}, lrow[2] = {0.f, 0.f};

    for (int j = 0; j <= qt; ++j) {
      __syncthreads();  // prior-iter LDS reads complete
#pragma unroll
      for (int i = 0; i < 4; ++i) {
        int c = tid + i * 256;
        *(uint4*)(k_lds + (c >> 3) * 72 + (c & 7) * 8) =
            *(const uint4*)(kbase + (size_t)(j * 128 + (c >> 3)) * DD + (c & 7) * 8);
      }
#pragma unroll
      for (int i = 0; i < 4; ++i) {
        int c = tid + i * 256;
        *(uint4*)(vt_lds + (c >> 4) * 130 + (c & 15) * 8) =
            *(const uint4*)(vtbase + (size_t)(c >> 4) * SS + j * 128 + (c & 15) * 8);
      }
      __syncthreads();  // staging visible

      // S^T = K · Q^T   (s[qtile][kf]: key = kf*16+quad*4+r, q = qtile*16+l16)
      f32x4 s[2][8];
#pragma unroll
      for (int qtile = 0; qtile < 2; ++qtile)
#pragma unroll
        for (int kf = 0; kf < 8; ++kf) s[qtile][kf] = f32x4{0.f, 0.f, 0.f, 0.f};
#pragma unroll
      for (int kf = 0; kf < 8; ++kf) {
        b16v8 kf0 = *(const b16v8*)(k_lds + (kf * 16 + l16) * 72 + quad * 8);
        b16v8 kf1 = *(const b16v8*)(k_lds + (kf * 16 + l16) * 72 + 32 + quad * 8);
#pragma unroll
        for (int qtile = 0; qtile < 2; ++qtile) {
          s[qtile][kf] = __builtin_amdgcn_mfma_f32_16x16x32_bf16(kf0, qf[qtile][0], s[qtile][kf], 0, 0, 0);
          s[qtile][kf] = __builtin_amdgcn_mfma_f32_16x16x32_bf16(kf1, qf[qtile][1], s[qtile][kf], 0, 0, 0);
        }
      }
      // causal mask on diagonal tile only
      if (j == qt) {
#pragma unroll
        for (int qtile = 0; qtile < 2; ++qtile) {
          int ql = w * 32 + qtile * 16 + l16;
#pragma unroll
          for (int kf = 0; kf < 8; ++kf)
#pragma unroll
            for (int r = 0; r < 4; ++r)
              if (kf * 16 + quad * 4 + r > ql) s[qtile][kf][r] = -1e30f;
        }
      }
      // online softmax (values already in log2 domain; q pre-scaled by 0.125*log2e)
#pragma unroll
      for (int qtile = 0; qtile < 2; ++qtile) {
        float mx = s[qtile][0][0];
#pragma unroll
        for (int kf = 0; kf < 8; ++kf)
#pragma unroll
          for (int r = 0; r < 4; ++r) mx = fmaxf(mx, s[qtile][kf][r]);
        mx = fmaxf(mx, __shfl_xor(mx, 16));
        mx = fmaxf(mx, __shfl_xor(mx, 32));
        float mn = fmaxf(mrow[qtile], mx);
        float alpha = __builtin_amdgcn_exp2f(mrow[qtile] - mn);
        mrow[qtile] = mn;
        float rs = 0.f;
#pragma unroll
        for (int kf = 0; kf < 8; ++kf)
#pragma unroll
          for (int r = 0; r < 4; ++r) {
            float pv = __builtin_amdgcn_exp2f(s[qtile][kf][r] - mn);
            s[qtile][kf][r] = pv;
            rs += pv;
          }
        rs += __shfl_xor(rs, 16);
        rs += __shfl_xor(rs, 32);
        lrow[qtile] = lrow[qtile] * alpha + rs;
#pragma unroll
        for (int dt = 0; dt < 4; ++dt)
#pragma unroll
          for (int r = 0; r < 4; ++r) o[dt][qtile][r] *= alpha;
      }
      // O^T += V^T · P^T  (P^T already in B-operand layout of 16x16x16)
#pragma unroll
      for (int kf = 0; kf < 8; ++kf) {
        b16v4 pf[2];
#pragma unroll
        for (int qtile = 0; qtile < 2; ++qtile) {
          b16v4 pk = {(__bf16)s[qtile][kf][0], (__bf16)s[qtile][kf][1],
                      (__bf16)s[qtile][kf][2], (__bf16)s[qtile][kf][3]};
          pf[qtile] = pk;
        }
#pragma unroll
        for (int dt = 0; dt < 4; ++dt) {
          b16v4 vf = *(const b16v4*)(vt_lds + (dt * 16 + l16) * 130 + kf * 16 + quad * 4);
#pragma unroll
          for (int qtile = 0; qtile < 2; ++qtile)
            o[dt][qtile] = mfma16x16x16_bf16(vf, pf[qtile], o[dt][qtile]);
        }
      }
    }

    // finalize: O^T / l, write y[b][q][h*64 + d]
#pragma unroll
    for (int qtile = 0; qtile < 2; ++qtile) {
      float inv = 1.0f / lrow[qtile];
      int q = qt * 128 + w * 32 + qtile * 16 + l16;
#pragma unroll
      for (int dt = 0; dt < 4; ++dt) {
        b16v4 ov = {(__bf16)(o[dt][qtile][0] * inv), (__bf16)(o[dt][qtile][1] * inv),
                    (__bf16)(o[dt][qtile][2] * inv), (__bf16)(o[dt][qtile][3] * inv)};
        *(b16v4*)(y + ((size_t)b * SS + q) * EE + h * 64 + dt * 16 + quad * 4) = ov;
      }
    }
  }
}

extern "C" void kernel_launch(void* const* d_in, const int* in_sizes, int n_in,
                              void* d_out, int out_size, void* d_ws, size_t ws_size,
                              hipStream_t stream) {
  (void)in_sizes; (void)n_in; (void)out_size; (void)ws_size;
  const float* x = (const float*)d_in[0];
  const float* w_att = (const float*)d_in[1];
  const float* w_proj = (const float*)d_in[2];
  float* out = (float*)d_out;

  char* ws = (char*)d_ws;
  size_t off = 0;
  auto alloc = [&](size_t elems) { __bf16* p = (__bf16*)(ws + off); off += elems * 2; return p; };
  __bf16* xb = alloc(8388608);     // x bf16; reused as y after attention
  __bf16* qb = alloc(8388608);     // [BH][S][D] (pre-scaled by 0.125*log2e)
  __bf16* kb = alloc(8388608);     // [BH][S][D]
  __bf16* vb = alloc(8388608);     // [BH][S][D]
  __bf16* vtb = alloc(8388608);    // [BH][D][S]
  __bf16* watt = alloc(3145728);   // w_att^T  [3072][1024]
  __bf16* wproj = alloc(1048576);  // w_proj^T [1024][1024]

  cast_x_kernel<<<8192, 256, 0, stream>>>(x, xb, 2097152);
  cast_transpose<<<dim3(96, 32), 256, 0, stream>>>(w_att, watt, 1024, 3072);
  cast_transpose<<<dim3(32, 32), 256, 0, stream>>>(w_proj, wproj, 1024, 1024);
  gemm_bt<0><<<dim3(24, 64), 256, 0, stream>>>(xb, watt, qb, kb, vb, 8192, 3072, 1024);
  transpose_v<<<dim3(32, 64), 256, 0, stream>>>(vb, vtb);
  attn_kernel<<<dim3(8, 64), 256, 0, stream>>>(qb, kb, vtb, xb);
  gemm_bt<1><<<dim3(8, 64), 256, 0, stream>>>(xb, wproj, out, nullptr, nullptr, 8192, 1024, 1024);
}

// Round 3
// 265.612 us; speedup vs baseline: 1.7172x; 1.3814x over previous
//
#include <hip/hip_runtime.h>
#include <hip/hip_bf16.h>

typedef __bf16 b16v8 __attribute__((ext_vector_type(8)));
typedef __bf16 b16v4 __attribute__((ext_vector_type(4)));
typedef float  f32x4 __attribute__((ext_vector_type(4)));

#define BB 4
#define SS 2048
#define EE 1024
#define HH 16
#define DD 64

// 0.125 * log2(e): folds softmax scale + exp->exp2 conversion into q.
#define QSCALE 0.18033688011112042f

__device__ __forceinline__ void async16(const __bf16* g, __bf16* l) {
  typedef __attribute__((address_space(1))) const unsigned int gu32;
  typedef __attribute__((address_space(3))) unsigned int lu32;
  __builtin_amdgcn_global_load_lds((gu32*)g, (lu32*)l, 16, 0, 0);
}

__device__ __forceinline__ f32x4 mfma16x16x16_bf16(b16v4 a, b16v4 b, f32x4 c) {
#if __has_builtin(__builtin_amdgcn_mfma_f32_16x16x16_bf16)
  return __builtin_amdgcn_mfma_f32_16x16x16_bf16(a, b, c, 0, 0, 0);
#else
  typedef short s16v4 __attribute__((ext_vector_type(4)));
  union U { b16v4 h; s16v4 s; };
  U ua, ub; ua.h = a; ub.h = b;
  return __builtin_amdgcn_mfma_f32_16x16x16bf16_1k(ua.s, ub.s, c, 0, 0, 0);
#endif
}

// ---------------- cast x (fp32 -> bf16), 4 elems/thread ----------------
__global__ __launch_bounds__(256) void cast_x_kernel(const float* __restrict__ in,
                                                     __bf16* __restrict__ out, int n4) {
  int i = blockIdx.x * 256 + threadIdx.x;
  if (i >= n4) return;
  float4 f = ((const float4*)in)[i];
  b16v4 o = {(__bf16)f.x, (__bf16)f.y, (__bf16)f.z, (__bf16)f.w};
  ((b16v4*)out)[i] = o;
}

// -------- cast + transpose weight: w[K][N] fp32 -> wt[N][K] bf16 --------
__global__ __launch_bounds__(256) void cast_transpose(const float* __restrict__ w,
                                                      __bf16* __restrict__ wt, int K, int N) {
  __shared__ float t[32][33];
  int n0 = blockIdx.x * 32, k0 = blockIdx.y * 32;
  int tx = threadIdx.x & 31, ty = threadIdx.x >> 5;  // 32x8
#pragma unroll
  for (int j = 0; j < 32; j += 8)
    t[ty + j][tx] = w[(size_t)(k0 + ty + j) * N + n0 + tx];
  __syncthreads();
#pragma unroll
  for (int j = 0; j < 32; j += 8)
    wt[(size_t)(n0 + ty + j) * K + k0 + tx] = (__bf16)t[tx][ty + j];
}

// ------------- transpose v [BH][S][D] -> vt [BH][D][S] (bf16) -------------
__global__ __launch_bounds__(256) void transpose_v(const __bf16* __restrict__ vb,
                                                   __bf16* __restrict__ vtb) {
  __shared__ __bf16 t[64 * 72];
  const int s0 = blockIdx.x * 64;
  const int bh = blockIdx.y;
  const int tid = threadIdx.x;
  const __bf16* src = vb + ((size_t)bh * SS + s0) * DD;
#pragma unroll
  for (int i = 0; i < 2; ++i) {
    int c = tid + i * 256;
    *(uint4*)(t + (c >> 3) * 72 + (c & 7) * 8) =
        *(const uint4*)(src + (size_t)(c >> 3) * DD + (c & 7) * 8);
  }
  __syncthreads();
  __bf16* dst = vtb + (size_t)bh * DD * SS + s0;
#pragma unroll
  for (int i = 0; i < 2; ++i) {
    int c = tid + i * 256;
    int d = c >> 3, s8 = c & 7;
    union { __bf16 e[8]; uint4 v; } u;
#pragma unroll
    for (int k = 0; k < 8; ++k) u.e[k] = t[(s8 * 8 + k) * 72 + d];
    *(uint4*)(dst + (size_t)d * SS + s8 * 8) = u.v;
  }
}

// ---------------- GEMM C[M][N] = A[M][K] * Bt[N][K]^T (bf16 in) ----------------
// EPI 0: scatter qkv (N=3072) into q/k/v [BH][S][D] bf16 (q pre-scaled). EPI 1: fp32 C0.
template <int EPI>
__global__ __launch_bounds__(256) void gemm_bt(const __bf16* __restrict__ A,
                                               const __bf16* __restrict__ Bt,
                                               void* C0, void* C1, void* C2,
                                               int M, int N, int K) {
  __shared__ __bf16 a_lds[128 * 32];
  __shared__ __bf16 b_lds[128 * 32];
  const int tid = threadIdx.x;
  const int lane = tid & 63;
  const int w = tid >> 6;
  const int wm = (w >> 1) * 64, wn = (w & 1) * 64;
  const int l16 = lane & 15, quad = lane >> 4;
  const __bf16* Ab = A + (size_t)blockIdx.y * 128 * K;
  const __bf16* Bb = Bt + (size_t)blockIdx.x * 128 * K;
  f32x4 acc[4][4];
#pragma unroll
  for (int i = 0; i < 4; ++i)
#pragma unroll
    for (int j = 0; j < 4; ++j) acc[i][j] = f32x4{0.f, 0.f, 0.f, 0.f};

  for (int k0 = 0; k0 < K; k0 += 32) {
    __syncthreads();
#pragma unroll
    for (int i = 0; i < 2; ++i) {
      int c = tid + i * 256;
      async16(Ab + (size_t)(c >> 2) * K + k0 + (c & 3) * 8, a_lds + c * 8);
    }
#pragma unroll
    for (int i = 0; i < 2; ++i) {
      int c = tid + i * 256;
      async16(Bb + (size_t)(c >> 2) * K + k0 + (c & 3) * 8, b_lds + c * 8);
    }
    __syncthreads();
    b16v8 af[4], bf[4];
#pragma unroll
    for (int t = 0; t < 4; ++t) {
      af[t] = *(const b16v8*)(a_lds + (wm + t * 16 + l16) * 32 + quad * 8);
      bf[t] = *(const b16v8*)(b_lds + (wn + t * 16 + l16) * 32 + quad * 8);
    }
#pragma unroll
    for (int mt = 0; mt < 4; ++mt)
#pragma unroll
      for (int nt = 0; nt < 4; ++nt)
        acc[mt][nt] = __builtin_amdgcn_mfma_f32_16x16x32_bf16(af[mt], bf[nt], acc[mt][nt], 0, 0, 0);
  }

  if (EPI == 0) {
    __bf16* qb = (__bf16*)C0;
    __bf16* kb = (__bf16*)C1;
    __bf16* vb = (__bf16*)C2;
#pragma unroll
    for (int mt = 0; mt < 4; ++mt)
#pragma unroll
      for (int nt = 0; nt < 4; ++nt)
#pragma unroll
        for (int r = 0; r < 4; ++r) {
          int row = blockIdx.y * 128 + wm + mt * 16 + quad * 4 + r;
          int col = blockIdx.x * 128 + wn + nt * 16 + l16;
          float v = acc[mt][nt][r];
          int b = row >> 11, s = row & 2047;
          int sec = col >> 10, cc = col & 1023;
          int h = cc >> 6, d = cc & 63;
          size_t idx = (((size_t)(b * HH + h) * SS + s) << 6) + d;
          if (sec == 0) qb[idx] = (__bf16)(v * QSCALE);
          else if (sec == 1) kb[idx] = (__bf16)v;
          else vb[idx] = (__bf16)v;
        }
  } else {
    float* out = (float*)C0;
#pragma unroll
    for (int mt = 0; mt < 4; ++mt)
#pragma unroll
      for (int nt = 0; nt < 4; ++nt)
#pragma unroll
        for (int r = 0; r < 4; ++r) {
          int row = blockIdx.y * 128 + wm + mt * 16 + quad * 4 + r;
          int col = blockIdx.x * 128 + wn + nt * 16 + l16;
          out[(size_t)row * N + col] = acc[mt][nt][r];
        }
  }
}

// ---------------- flash attention (causal), S^T/O^T + async DMA double-buffer ----
// Block p handles q-tiles {15-p, p}. S^T = K·Q^T (16x16x32, operand swap); P^T in
// registers == B-operand of 16x16x16 => PV with zero data movement.
// K/V^T tiles: global_load_lds DMA, XOR-swizzled (16B chunk ^ row) unpadded LDS,
// ping-pong buffers, ONE barrier per j-iter; tile j+1 DMA covered by compute(j).
__global__ __launch_bounds__(256, 2) void attn_kernel(const __bf16* __restrict__ qb,
                                                      const __bf16* __restrict__ kb,
                                                      const __bf16* __restrict__ vtb,
                                                      __bf16* __restrict__ y) {
  // [buf][ K tile 128x64 (8192) | V^T tile 64x128 (8192) ]  = 64 KB total
  __shared__ __bf16 kv_lds[2][16384];
  const int tid = threadIdx.x;
  const int lane = tid & 63;
  const int w = tid >> 6;
  const int l16 = lane & 15, quad = lane >> 4;
  const int p = blockIdx.x, bh = blockIdx.y;
  const int b = bh >> 4, h = bh & 15;
  const __bf16* kbase = kb + (size_t)bh * SS * DD;
  const __bf16* vtbase = vtb + (size_t)bh * DD * SS;

  // DMA-stage tile j into buf: K [row 0..127][8 chunks], slot c holds global chunk c^(row&7);
  // V^T [d 0..63][16 chunks], slot c holds global chunk c^(d&15).
  auto stage = [&](int j, __bf16* buf) {
#pragma unroll
    for (int i = 0; i < 4; ++i) {
      int L = w * 256 + i * 64 + lane;
      int row = L >> 3, c = L & 7;
      async16(kbase + (size_t)(j * 128 + row) * DD + ((c ^ (row & 7)) * 8), buf + L * 8);
    }
#pragma unroll
    for (int i = 0; i < 4; ++i) {
      int L = w * 256 + i * 64 + lane;
      int d = L >> 4, c = L & 15;
      async16(vtbase + (size_t)d * SS + j * 128 + ((c ^ (d & 15)) * 8), buf + 8192 + L * 8);
    }
  };

#pragma unroll
  for (int t = 0; t < 2; ++t) {
    const int qt = (t == 0) ? (15 - p) : p;

    // Q frags: lane holds Q[q = qt*128 + w*32 + qtile*16 + l16][d = ks*32 + quad*8 + j]
    b16v8 qf[2][2];
#pragma unroll
    for (int qtile = 0; qtile < 2; ++qtile)
#pragma unroll
      for (int ks = 0; ks < 2; ++ks)
        qf[qtile][ks] = *(const b16v8*)(qb + ((size_t)bh * SS + qt * 128 + w * 32 + qtile * 16 + l16) * DD + ks * 32 + quad * 8);

    f32x4 o[4][2];  // O^T[d = dt*16+quad*4+r][q = qtile*16+l16]
#pragma unroll
    for (int dt = 0; dt < 4; ++dt)
#pragma unroll
      for (int qtile = 0; qtile < 2; ++qtile) o[dt][qtile] = f32x4{0.f, 0.f, 0.f, 0.f};
    float mrow[2] = {-1e30f, -1e30f}, lrow[2] = {0.f, 0.f};

    __syncthreads();           // prior q-tile's readers done before overwriting buf0
    stage(0, kv_lds[0]);       // prologue DMA (zero-cover, once per q-tile)

    for (int j = 0; j <= qt; ++j) {
      __syncthreads();  // drains vmcnt: tile j ready; buf[(j+1)&1] readers (iter j-1) done
      if (j < qt) stage(j + 1, kv_lds[(j + 1) & 1]);  // DMA covered by compute(j)
      const __bf16* kbuf = kv_lds[j & 1];
      const __bf16* vbuf = kbuf + 8192;

      // S^T = K · Q^T   (s[qtile][kf]: key = kf*16+quad*4+r, q = qtile*16+l16)
      f32x4 s[2][8];
#pragma unroll
      for (int qtile = 0; qtile < 2; ++qtile)
#pragma unroll
        for (int kf = 0; kf < 8; ++kf) s[qtile][kf] = f32x4{0.f, 0.f, 0.f, 0.f};
#pragma unroll
      for (int kf = 0; kf < 8; ++kf) {
        int rb = kf * 16 + l16;
        b16v8 kf0 = *(const b16v8*)(kbuf + rb * DD + ((quad ^ (rb & 7)) * 8));
        b16v8 kf1 = *(const b16v8*)(kbuf + rb * DD + (((quad + 4) ^ (rb & 7)) * 8));
#pragma unroll
        for (int qtile = 0; qtile < 2; ++qtile) {
          s[qtile][kf] = __builtin_amdgcn_mfma_f32_16x16x32_bf16(kf0, qf[qtile][0], s[qtile][kf], 0, 0, 0);
          s[qtile][kf] = __builtin_amdgcn_mfma_f32_16x16x32_bf16(kf1, qf[qtile][1], s[qtile][kf], 0, 0, 0);
        }
      }
      // causal mask on diagonal tile only
      if (j == qt) {
#pragma unroll
        for (int qtile = 0; qtile < 2; ++qtile) {
          int ql = w * 32 + qtile * 16 + l16;
#pragma unroll
          for (int kf = 0; kf < 8; ++kf)
#pragma unroll
            for (int r = 0; r < 4; ++r)
              if (kf * 16 + quad * 4 + r > ql) s[qtile][kf][r] = -1e30f;
        }
      }
      // online softmax (log2 domain; q pre-scaled by 0.125*log2e)
#pragma unroll
      for (int qtile = 0; qtile < 2; ++qtile) {
        float mx = s[qtile][0][0];
#pragma unroll
        for (int kf = 0; kf < 8; ++kf)
#pragma unroll
          for (int r = 0; r < 4; ++r) mx = fmaxf(mx, s[qtile][kf][r]);
        mx = fmaxf(mx, __shfl_xor(mx, 16));
        mx = fmaxf(mx, __shfl_xor(mx, 32));
        float mn = fmaxf(mrow[qtile], mx);
        float alpha = __builtin_amdgcn_exp2f(mrow[qtile] - mn);
        mrow[qtile] = mn;
        float rs = 0.f;
#pragma unroll
        for (int kf = 0; kf < 8; ++kf)
#pragma unroll
          for (int r = 0; r < 4; ++r) {
            float pv = __builtin_amdgcn_exp2f(s[qtile][kf][r] - mn);
            s[qtile][kf][r] = pv;
            rs += pv;
          }
        rs += __shfl_xor(rs, 16);
        rs += __shfl_xor(rs, 32);
        lrow[qtile] = lrow[qtile] * alpha + rs;
#pragma unroll
        for (int dt = 0; dt < 4; ++dt)
#pragma unroll
          for (int r = 0; r < 4; ++r) o[dt][qtile][r] *= alpha;
      }
      // O^T += V^T · P^T  (P^T already in B-operand layout of 16x16x16)
#pragma unroll
      for (int kf = 0; kf < 8; ++kf) {
        b16v4 pf[2];
#pragma unroll
        for (int qtile = 0; qtile < 2; ++qtile) {
          b16v4 pk = {(__bf16)s[qtile][kf][0], (__bf16)s[qtile][kf][1],
                      (__bf16)s[qtile][kf][2], (__bf16)s[qtile][kf][3]};
          pf[qtile] = pk;
        }
        int cg = kf * 2 + (quad >> 1);
#pragma unroll
        for (int dt = 0; dt < 4; ++dt) {
          int d = dt * 16 + l16;
          b16v4 vf = *(const b16v4*)(vbuf + d * 128 + ((cg ^ l16) * 8) + ((quad & 1) * 4));
#pragma unroll
          for (int qtile = 0; qtile < 2; ++qtile)
            o[dt][qtile] = mfma16x16x16_bf16(vf, pf[qtile], o[dt][qtile]);
        }
      }
    }

    // finalize: O^T / l, write y[b][q][h*64 + d]
#pragma unroll
    for (int qtile = 0; qtile < 2; ++qtile) {
      float inv = 1.0f / lrow[qtile];
      int q = qt * 128 + w * 32 + qtile * 16 + l16;
#pragma unroll
      for (int dt = 0; dt < 4; ++dt) {
        b16v4 ov = {(__bf16)(o[dt][qtile][0] * inv), (__bf16)(o[dt][qtile][1] * inv),
                    (__bf16)(o[dt][qtile][2] * inv), (__bf16)(o[dt][qtile][3] * inv)};
        *(b16v4*)(y + ((size_t)b * SS + q) * EE + h * 64 + dt * 16 + quad * 4) = ov;
      }
    }
  }
}

extern "C" void kernel_launch(void* const* d_in, const int* in_sizes, int n_in,
                              void* d_out, int out_size, void* d_ws, size_t ws_size,
                              hipStream_t stream) {
  (void)in_sizes; (void)n_in; (void)out_size; (void)ws_size;
  const float* x = (const float*)d_in[0];
  const float* w_att = (const float*)d_in[1];
  const float* w_proj = (const float*)d_in[2];
  float* out = (float*)d_out;

  char* ws = (char*)d_ws;
  size_t off = 0;
  auto alloc = [&](size_t elems) { __bf16* p = (__bf16*)(ws + off); off += elems * 2; return p; };
  __bf16* xb = alloc(8388608);     // x bf16; reused as y after attention
  __bf16* qb = alloc(8388608);     // [BH][S][D] (pre-scaled by 0.125*log2e)
  __bf16* kb = alloc(8388608);     // [BH][S][D]
  __bf16* vb = alloc(8388608);     // [BH][S][D]
  __bf16* vtb = alloc(8388608);    // [BH][D][S]
  __bf16* watt = alloc(3145728);   // w_att^T  [3072][1024]
  __bf16* wproj = alloc(1048576);  // w_proj^T [1024][1024]

  cast_x_kernel<<<8192, 256, 0, stream>>>(x, xb, 2097152);
  cast_transpose<<<dim3(96, 32), 256, 0, stream>>>(w_att, watt, 1024, 3072);
  cast_transpose<<<dim3(32, 32), 256, 0, stream>>>(w_proj, wproj, 1024, 1024);
  gemm_bt<0><<<dim3(24, 64), 256, 0, stream>>>(xb, watt, qb, kb, vb, 8192, 3072, 1024);
  transpose_v<<<dim3(32, 64), 256, 0, stream>>>(vb, vtb);
  attn_kernel<<<dim3(8, 64), 256, 0, stream>>>(qb, kb, vtb, xb);
  gemm_bt<1><<<dim3(8, 64), 256, 0, stream>>>(xb, wproj, out, nullptr, nullptr, 8192, 1024, 1024);
}

// Round 4
// 256.633 us; speedup vs baseline: 1.7773x; 1.0350x over previous
//
#include <hip/hip_runtime.h>
#include <hip/hip_bf16.h>

typedef __bf16 b16v8 __attribute__((ext_vector_type(8)));
typedef __bf16 b16v4 __attribute__((ext_vector_type(4)));
typedef float  f32x4 __attribute__((ext_vector_type(4)));

#define BB 4
#define SS 2048
#define EE 1024
#define HH 16
#define DD 64

// 0.125 * log2(e): folds softmax scale + exp->exp2 conversion into q.
#define QSCALE 0.18033688011112042f

__device__ __forceinline__ void async16(const __bf16* g, __bf16* l) {
  typedef __attribute__((address_space(1))) const unsigned int gu32;
  typedef __attribute__((address_space(3))) unsigned int lu32;
  __builtin_amdgcn_global_load_lds((gu32*)g, (lu32*)l, 16, 0, 0);
}

__device__ __forceinline__ f32x4 mfma16x16x16_bf16(b16v4 a, b16v4 b, f32x4 c) {
#if __has_builtin(__builtin_amdgcn_mfma_f32_16x16x16_bf16)
  return __builtin_amdgcn_mfma_f32_16x16x16_bf16(a, b, c, 0, 0, 0);
#else
  typedef short s16v4 __attribute__((ext_vector_type(4)));
  union U { b16v4 h; s16v4 s; };
  U ua, ub; ua.h = a; ub.h = b;
  return __builtin_amdgcn_mfma_f32_16x16x16bf16_1k(ua.s, ub.s, c, 0, 0, 0);
#endif
}

// ---------------- cast x (fp32 -> bf16), 4 elems/thread ----------------
__global__ __launch_bounds__(256) void cast_x_kernel(const float* __restrict__ in,
                                                     __bf16* __restrict__ out, int n4) {
  int i = blockIdx.x * 256 + threadIdx.x;
  if (i >= n4) return;
  float4 f = ((const float4*)in)[i];
  b16v4 o = {(__bf16)f.x, (__bf16)f.y, (__bf16)f.z, (__bf16)f.w};
  ((b16v4*)out)[i] = o;
}

// -------- cast + transpose weight: w[K][N] fp32 -> wt[N][K] bf16 --------
__global__ __launch_bounds__(256) void cast_transpose(const float* __restrict__ w,
                                                      __bf16* __restrict__ wt, int K, int N) {
  __shared__ float t[32][33];
  int n0 = blockIdx.x * 32, k0 = blockIdx.y * 32;
  int tx = threadIdx.x & 31, ty = threadIdx.x >> 5;  // 32x8
#pragma unroll
  for (int j = 0; j < 32; j += 8)
    t[ty + j][tx] = w[(size_t)(k0 + ty + j) * N + n0 + tx];
  __syncthreads();
#pragma unroll
  for (int j = 0; j < 32; j += 8)
    wt[(size_t)(n0 + ty + j) * K + k0 + tx] = (__bf16)t[tx][ty + j];
}

// ---------------- GEMM C[M][N] = A[M][K] * Bt[N][K]^T (bf16 in) ----------------
// Double-buffered global_load_lds staging, ONE barrier per K-iter (DMA for tile
// k+1 covered by compute of tile k). XOR-swizzled chunks (c^(row&3)) for LDS.
// EPI 0: scatter qkv (N=3072): q (pre-scaled), k -> [BH][S][D]; v -> vt [BH][D][S]
// directly (transposed store: acc's 4 rows are consecutive s at fixed d).
// EPI 1: fp32 C0[M][N].
template <int EPI>
__global__ __launch_bounds__(256) void gemm_bt(const __bf16* __restrict__ A,
                                               const __bf16* __restrict__ Bt,
                                               void* C0, void* C1, void* C2,
                                               int M, int N, int K) {
  __shared__ __bf16 a_lds[2][128 * 32];
  __shared__ __bf16 b_lds[2][128 * 32];
  const int tid = threadIdx.x;
  const int lane = tid & 63;
  const int w = tid >> 6;
  const int wm = (w >> 1) * 64, wn = (w & 1) * 64;
  const int l16 = lane & 15, quad = lane >> 4;
  const __bf16* Ab = A + (size_t)blockIdx.y * 128 * K;
  const __bf16* Bb = Bt + (size_t)blockIdx.x * 128 * K;

  auto stage = [&](int k0, int bufi) {
#pragma unroll
    for (int i = 0; i < 2; ++i) {
      int c = tid + i * 256;
      int row = c >> 2, ch = c & 3;
      async16(Ab + (size_t)row * K + k0 + ((ch ^ (row & 3)) * 8), a_lds[bufi] + c * 8);
    }
#pragma unroll
    for (int i = 0; i < 2; ++i) {
      int c = tid + i * 256;
      int row = c >> 2, ch = c & 3;
      async16(Bb + (size_t)row * K + k0 + ((ch ^ (row & 3)) * 8), b_lds[bufi] + c * 8);
    }
  };

  f32x4 acc[4][4];
#pragma unroll
  for (int i = 0; i < 4; ++i)
#pragma unroll
    for (int j = 0; j < 4; ++j) acc[i][j] = f32x4{0.f, 0.f, 0.f, 0.f};

  stage(0, 0);
  const int KT = K >> 5;
  const int sw = (quad ^ (l16 & 3)) * 8;
  for (int kt = 0; kt < KT; ++kt) {
    __syncthreads();  // vmcnt drain: tile kt staged; prior readers of other buf done
    if (kt + 1 < KT) stage((kt + 1) << 5, (kt + 1) & 1);
    const __bf16* ab = a_lds[kt & 1];
    const __bf16* bb = b_lds[kt & 1];
    b16v8 af[4], bf4[4];
#pragma unroll
    for (int t = 0; t < 4; ++t) {
      af[t] = *(const b16v8*)(ab + (wm + t * 16 + l16) * 32 + sw);
      bf4[t] = *(const b16v8*)(bb + (wn + t * 16 + l16) * 32 + sw);
    }
#pragma unroll
    for (int mt = 0; mt < 4; ++mt)
#pragma unroll
      for (int nt = 0; nt < 4; ++nt)
        acc[mt][nt] = __builtin_amdgcn_mfma_f32_16x16x32_bf16(af[mt], bf4[nt], acc[mt][nt], 0, 0, 0);
  }

  if (EPI == 0) {
    __bf16* qb = (__bf16*)C0;
    __bf16* kb = (__bf16*)C1;
    __bf16* vtb = (__bf16*)C2;
#pragma unroll
    for (int mt = 0; mt < 4; ++mt)
#pragma unroll
      for (int nt = 0; nt < 4; ++nt) {
        int row = blockIdx.y * 128 + wm + mt * 16 + quad * 4;  // s of r=0 (tile 128-aligned)
        int col = blockIdx.x * 128 + wn + nt * 16 + l16;
        int b = row >> 11, s = row & 2047;
        int sec = col >> 10, cc = col & 1023;
        int h = cc >> 6, d = cc & 63;
        if (sec == 2) {
          b16v4 vv = {(__bf16)acc[mt][nt][0], (__bf16)acc[mt][nt][1],
                      (__bf16)acc[mt][nt][2], (__bf16)acc[mt][nt][3]};
          *(b16v4*)(vtb + ((size_t)(b * HH + h) * DD + d) * SS + s) = vv;
        } else {
          __bf16* dst = (sec == 0) ? qb : kb;
          float sc = (sec == 0) ? QSCALE : 1.0f;
#pragma unroll
          for (int r = 0; r < 4; ++r)
            dst[(((size_t)(b * HH + h) * SS + s + r) << 6) + d] = (__bf16)(acc[mt][nt][r] * sc);
        }
      }
  } else {
    float* out = (float*)C0;
#pragma unroll
    for (int mt = 0; mt < 4; ++mt)
#pragma unroll
      for (int nt = 0; nt < 4; ++nt)
#pragma unroll
        for (int r = 0; r < 4; ++r) {
          int row = blockIdx.y * 128 + wm + mt * 16 + quad * 4 + r;
          int col = blockIdx.x * 128 + wn + nt * 16 + l16;
          out[(size_t)row * N + col] = acc[mt][nt][r];
        }
  }
}

// ---------------- flash attention (causal), S^T/O^T + async DMA double-buffer ----
// Block p handles q-tiles {15-p, p}. S^T = K·Q^T (16x16x32, operand swap); P^T in
// registers == B-operand of 16x16x16 => PV with zero data movement.
// K/V^T tiles: global_load_lds DMA, XOR-swizzled (16B chunk ^ row) unpadded LDS,
// ping-pong buffers, ONE barrier per j-iter; tile j+1 DMA covered by compute(j).
__global__ __launch_bounds__(256, 2) void attn_kernel(const __bf16* __restrict__ qb,
                                                      const __bf16* __restrict__ kb,
                                                      const __bf16* __restrict__ vtb,
                                                      __bf16* __restrict__ y) {
  // [buf][ K tile 128x64 (8192) | V^T tile 64x128 (8192) ]  = 64 KB total
  __shared__ __bf16 kv_lds[2][16384];
  const int tid = threadIdx.x;
  const int lane = tid & 63;
  const int w = tid >> 6;
  const int l16 = lane & 15, quad = lane >> 4;
  const int p = blockIdx.x, bh = blockIdx.y;
  const int b = bh >> 4, h = bh & 15;
  const __bf16* kbase = kb + (size_t)bh * SS * DD;
  const __bf16* vtbase = vtb + (size_t)bh * DD * SS;

  // DMA-stage tile j into buf: K [row 0..127][8 chunks], slot c holds global chunk c^(row&7);
  // V^T [d 0..63][16 chunks], slot c holds global chunk c^(d&15).
  auto stage = [&](int j, __bf16* buf) {
#pragma unroll
    for (int i = 0; i < 4; ++i) {
      int L = w * 256 + i * 64 + lane;
      int row = L >> 3, c = L & 7;
      async16(kbase + (size_t)(j * 128 + row) * DD + ((c ^ (row & 7)) * 8), buf + L * 8);
    }
#pragma unroll
    for (int i = 0; i < 4; ++i) {
      int L = w * 256 + i * 64 + lane;
      int d = L >> 4, c = L & 15;
      async16(vtbase + (size_t)d * SS + j * 128 + ((c ^ (d & 15)) * 8), buf + 8192 + L * 8);
    }
  };

#pragma unroll
  for (int t = 0; t < 2; ++t) {
    const int qt = (t == 0) ? (15 - p) : p;

    // Q frags: lane holds Q[q = qt*128 + w*32 + qtile*16 + l16][d = ks*32 + quad*8 + j]
    b16v8 qf[2][2];
#pragma unroll
    for (int qtile = 0; qtile < 2; ++qtile)
#pragma unroll
      for (int ks = 0; ks < 2; ++ks)
        qf[qtile][ks] = *(const b16v8*)(qb + ((size_t)bh * SS + qt * 128 + w * 32 + qtile * 16 + l16) * DD + ks * 32 + quad * 8);

    f32x4 o[4][2];  // O^T[d = dt*16+quad*4+r][q = qtile*16+l16]
#pragma unroll
    for (int dt = 0; dt < 4; ++dt)
#pragma unroll
      for (int qtile = 0; qtile < 2; ++qtile) o[dt][qtile] = f32x4{0.f, 0.f, 0.f, 0.f};
    float mrow[2] = {-1e30f, -1e30f}, lrow[2] = {0.f, 0.f};

    __syncthreads();           // prior q-tile's readers done before overwriting buf0
    stage(0, kv_lds[0]);       // prologue DMA (zero-cover, once per q-tile)

    for (int j = 0; j <= qt; ++j) {
      __syncthreads();  // drains vmcnt: tile j ready; buf[(j+1)&1] readers (iter j-1) done
      if (j < qt) stage(j + 1, kv_lds[(j + 1) & 1]);  // DMA covered by compute(j)
      const __bf16* kbuf = kv_lds[j & 1];
      const __bf16* vbuf = kbuf + 8192;

      // S^T = K · Q^T   (s[qtile][kf]: key = kf*16+quad*4+r, q = qtile*16+l16)
      f32x4 s[2][8];
#pragma unroll
      for (int qtile = 0; qtile < 2; ++qtile)
#pragma unroll
        for (int kf = 0; kf < 8; ++kf) s[qtile][kf] = f32x4{0.f, 0.f, 0.f, 0.f};
#pragma unroll
      for (int kf = 0; kf < 8; ++kf) {
        int rb = kf * 16 + l16;
        b16v8 kf0 = *(const b16v8*)(kbuf + rb * DD + ((quad ^ (rb & 7)) * 8));
        b16v8 kf1 = *(const b16v8*)(kbuf + rb * DD + (((quad + 4) ^ (rb & 7)) * 8));
#pragma unroll
        for (int qtile = 0; qtile < 2; ++qtile) {
          s[qtile][kf] = __builtin_amdgcn_mfma_f32_16x16x32_bf16(kf0, qf[qtile][0], s[qtile][kf], 0, 0, 0);
          s[qtile][kf] = __builtin_amdgcn_mfma_f32_16x16x32_bf16(kf1, qf[qtile][1], s[qtile][kf], 0, 0, 0);
        }
      }
      // causal mask on diagonal tile only
      if (j == qt) {
#pragma unroll
        for (int qtile = 0; qtile < 2; ++qtile) {
          int ql = w * 32 + qtile * 16 + l16;
#pragma unroll
          for (int kf = 0; kf < 8; ++kf)
#pragma unroll
            for (int r = 0; r < 4; ++r)
              if (kf * 16 + quad * 4 + r > ql) s[qtile][kf][r] = -1e30f;
        }
      }
      // online softmax (log2 domain; q pre-scaled by 0.125*log2e)
#pragma unroll
      for (int qtile = 0; qtile < 2; ++qtile) {
        float mx = s[qtile][0][0];
#pragma unroll
        for (int kf = 0; kf < 8; ++kf)
#pragma unroll
          for (int r = 0; r < 4; ++r) mx = fmaxf(mx, s[qtile][kf][r]);
        mx = fmaxf(mx, __shfl_xor(mx, 16));
        mx = fmaxf(mx, __shfl_xor(mx, 32));
        float mn = fmaxf(mrow[qtile], mx);
        float alpha = __builtin_amdgcn_exp2f(mrow[qtile] - mn);
        mrow[qtile] = mn;
        float rs = 0.f;
#pragma unroll
        for (int kf = 0; kf < 8; ++kf)
#pragma unroll
          for (int r = 0; r < 4; ++r) {
            float pv = __builtin_amdgcn_exp2f(s[qtile][kf][r] - mn);
            s[qtile][kf][r] = pv;
            rs += pv;
          }
        rs += __shfl_xor(rs, 16);
        rs += __shfl_xor(rs, 32);
        lrow[qtile] = lrow[qtile] * alpha + rs;
#pragma unroll
        for (int dt = 0; dt < 4; ++dt)
#pragma unroll
          for (int r = 0; r < 4; ++r) o[dt][qtile][r] *= alpha;
      }
      // O^T += V^T · P^T  (P^T already in B-operand layout of 16x16x16)
#pragma unroll
      for (int kf = 0; kf < 8; ++kf) {
        b16v4 pf[2];
#pragma unroll
        for (int qtile = 0; qtile < 2; ++qtile) {
          b16v4 pk = {(__bf16)s[qtile][kf][0], (__bf16)s[qtile][kf][1],
                      (__bf16)s[qtile][kf][2], (__bf16)s[qtile][kf][3]};
          pf[qtile] = pk;
        }
        int cg = kf * 2 + (quad >> 1);
#pragma unroll
        for (int dt = 0; dt < 4; ++dt) {
          int d = dt * 16 + l16;
          b16v4 vf = *(const b16v4*)(vbuf + d * 128 + ((cg ^ l16) * 8) + ((quad & 1) * 4));
#pragma unroll
          for (int qtile = 0; qtile < 2; ++qtile)
            o[dt][qtile] = mfma16x16x16_bf16(vf, pf[qtile], o[dt][qtile]);
        }
      }
    }

    // finalize: O^T / l, write y[b][q][h*64 + d]
#pragma unroll
    for (int qtile = 0; qtile < 2; ++qtile) {
      float inv = 1.0f / lrow[qtile];
      int q = qt * 128 + w * 32 + qtile * 16 + l16;
#pragma unroll
      for (int dt = 0; dt < 4; ++dt) {
        b16v4 ov = {(__bf16)(o[dt][qtile][0] * inv), (__bf16)(o[dt][qtile][1] * inv),
                    (__bf16)(o[dt][qtile][2] * inv), (__bf16)(o[dt][qtile][3] * inv)};
        *(b16v4*)(y + ((size_t)b * SS + q) * EE + h * 64 + dt * 16 + quad * 4) = ov;
      }
    }
  }
}

extern "C" void kernel_launch(void* const* d_in, const int* in_sizes, int n_in,
                              void* d_out, int out_size, void* d_ws, size_t ws_size,
                              hipStream_t stream) {
  (void)in_sizes; (void)n_in; (void)out_size; (void)ws_size;
  const float* x = (const float*)d_in[0];
  const float* w_att = (const float*)d_in[1];
  const float* w_proj = (const float*)d_in[2];
  float* out = (float*)d_out;

  char* ws = (char*)d_ws;
  size_t off = 0;
  auto alloc = [&](size_t elems) { __bf16* p = (__bf16*)(ws + off); off += elems * 2; return p; };
  __bf16* xb = alloc(8388608);     // x bf16; reused as y after attention
  __bf16* qb = alloc(8388608);     // [BH][S][D] (pre-scaled by 0.125*log2e)
  __bf16* kb = alloc(8388608);     // [BH][S][D]
  __bf16* vtb = alloc(8388608);    // [BH][D][S] (written transposed by gemm_bt<0>)
  __bf16* watt = alloc(3145728);   // w_att^T  [3072][1024]
  __bf16* wproj = alloc(1048576);  // w_proj^T [1024][1024]

  cast_x_kernel<<<8192, 256, 0, stream>>>(x, xb, 2097152);
  cast_transpose<<<dim3(96, 32), 256, 0, stream>>>(w_att, watt, 1024, 3072);
  cast_transpose<<<dim3(32, 32), 256, 0, stream>>>(w_proj, wproj, 1024, 1024);
  gemm_bt<0><<<dim3(24, 64), 256, 0, stream>>>(xb, watt, qb, kb, vtb, 8192, 3072, 1024);
  attn_kernel<<<dim3(8, 64), 256, 0, stream>>>(qb, kb, vtb, xb);
  gemm_bt<1><<<dim3(8, 64), 256, 0, stream>>>(xb, wproj, out, nullptr, nullptr, 8192, 1024, 1024);
}